// Round 1
// baseline (10731.434 us; speedup 1.0000x reference)
//
#include <hip/hip_runtime.h>
#include <math.h>

#define BB 64
#define SS 48
#define EE 256
#define HH 512
#define VV 30000
#define G3 1536  // 3*H

__device__ __forceinline__ float sigmoidf_(float x) { return 1.f / (1.f + expf(-x)); }

// ---------- tiny init ----------
__global__ void init_tok_kernel(int* tok) {
    if (threadIdx.x < BB) tok[threadIdx.x] = 0;
}

// ---------- gates GEMM: gi[j][b] = sum_k embed[tok[b]][k]*wih[j][k]
//                         gh[j][b] = sum_k hprev[b][k]*whh[j][k] ----------
// grid.x = G3/64 = 24, block = 256
__global__ __launch_bounds__(256) void gates_kernel(
    const int* __restrict__ tokens, int tok_stride,
    const float* __restrict__ embed,
    const float* __restrict__ wih, const float* __restrict__ whh,
    const float* __restrict__ hprev, int hstride,
    float* __restrict__ gi, float* __restrict__ gh)
{
    __shared__ float Wt[64][68];   // [k][j]
    __shared__ float Xt[64][68];   // [k][b]
    const int t  = threadIdx.x;
    const int tx = t & 15, ty = t >> 4;      // compute roles: b-quad, j-quad
    const int j0 = blockIdx.x * 64;
    const int bb = t & 63, kq = t >> 6;      // X staging roles
    const int wkk = (t & 15) * 4, wjj = t >> 4;  // W staging roles

    const long xrow = (long)tokens[bb * tok_stride] * EE;

    float acc[4][4];

    // ================= Phase A: gi (K = EE, W = wih) =================
    #pragma unroll
    for (int i = 0; i < 4; i++)
        #pragma unroll
        for (int j = 0; j < 4; j++) acc[i][j] = 0.f;

    for (int kb = 0; kb < EE; kb += 64) {
        #pragma unroll
        for (int r = 0; r < 4; r++) {
            int row = j0 + wjj + r * 16;
            const float4 w = *(const float4*)&wih[row * EE + kb + wkk];
            Wt[wkk + 0][wjj + r * 16] = w.x;
            Wt[wkk + 1][wjj + r * 16] = w.y;
            Wt[wkk + 2][wjj + r * 16] = w.z;
            Wt[wkk + 3][wjj + r * 16] = w.w;
        }
        {
            const float* src = embed + xrow + kb + kq * 16;
            #pragma unroll
            for (int q = 0; q < 4; q++) {
                const float4 x = *(const float4*)&src[q * 4];
                Xt[kq * 16 + q * 4 + 0][bb] = x.x;
                Xt[kq * 16 + q * 4 + 1][bb] = x.y;
                Xt[kq * 16 + q * 4 + 2][bb] = x.z;
                Xt[kq * 16 + q * 4 + 3][bb] = x.w;
            }
        }
        __syncthreads();
        #pragma unroll 8
        for (int k = 0; k < 64; k++) {
            const float4 a = *(const float4*)&Wt[k][ty * 4];
            const float4 x = *(const float4*)&Xt[k][tx * 4];
            acc[0][0] += a.x * x.x; acc[0][1] += a.x * x.y; acc[0][2] += a.x * x.z; acc[0][3] += a.x * x.w;
            acc[1][0] += a.y * x.x; acc[1][1] += a.y * x.y; acc[1][2] += a.y * x.z; acc[1][3] += a.y * x.w;
            acc[2][0] += a.z * x.x; acc[2][1] += a.z * x.y; acc[2][2] += a.z * x.z; acc[2][3] += a.z * x.w;
            acc[3][0] += a.w * x.x; acc[3][1] += a.w * x.y; acc[3][2] += a.w * x.z; acc[3][3] += a.w * x.w;
        }
        __syncthreads();
    }
    #pragma unroll
    for (int i = 0; i < 4; i++) {
        float4 o; o.x = acc[i][0]; o.y = acc[i][1]; o.z = acc[i][2]; o.w = acc[i][3];
        *(float4*)&gi[(j0 + ty * 4 + i) * BB + tx * 4] = o;
    }

    // ================= Phase B: gh (K = HH, W = whh) =================
    #pragma unroll
    for (int i = 0; i < 4; i++)
        #pragma unroll
        for (int j = 0; j < 4; j++) acc[i][j] = 0.f;

    if (hprev) {
        const float* hsrc = hprev + (long)bb * hstride;
        for (int kb = 0; kb < HH; kb += 64) {
            #pragma unroll
            for (int r = 0; r < 4; r++) {
                int row = j0 + wjj + r * 16;
                const float4 w = *(const float4*)&whh[row * HH + kb + wkk];
                Wt[wkk + 0][wjj + r * 16] = w.x;
                Wt[wkk + 1][wjj + r * 16] = w.y;
                Wt[wkk + 2][wjj + r * 16] = w.z;
                Wt[wkk + 3][wjj + r * 16] = w.w;
            }
            {
                const float* src = hsrc + kb + kq * 16;
                #pragma unroll
                for (int q = 0; q < 4; q++) {
                    const float4 x = *(const float4*)&src[q * 4];
                    Xt[kq * 16 + q * 4 + 0][bb] = x.x;
                    Xt[kq * 16 + q * 4 + 1][bb] = x.y;
                    Xt[kq * 16 + q * 4 + 2][bb] = x.z;
                    Xt[kq * 16 + q * 4 + 3][bb] = x.w;
                }
            }
            __syncthreads();
            #pragma unroll 8
            for (int k = 0; k < 64; k++) {
                const float4 a = *(const float4*)&Wt[k][ty * 4];
                const float4 x = *(const float4*)&Xt[k][tx * 4];
                acc[0][0] += a.x * x.x; acc[0][1] += a.x * x.y; acc[0][2] += a.x * x.z; acc[0][3] += a.x * x.w;
                acc[1][0] += a.y * x.x; acc[1][1] += a.y * x.y; acc[1][2] += a.y * x.z; acc[1][3] += a.y * x.w;
                acc[2][0] += a.z * x.x; acc[2][1] += a.z * x.y; acc[2][2] += a.z * x.z; acc[2][3] += a.z * x.w;
                acc[3][0] += a.w * x.x; acc[3][1] += a.w * x.y; acc[3][2] += a.w * x.z; acc[3][3] += a.w * x.w;
            }
            __syncthreads();
        }
    }
    #pragma unroll
    for (int i = 0; i < 4; i++) {
        float4 o; o.x = acc[i][0]; o.y = acc[i][1]; o.z = acc[i][2]; o.w = acc[i][3];
        *(float4*)&gh[(j0 + ty * 4 + i) * BB + tx * 4] = o;
    }
}

// ---------- GRU gate combine: h_new[b][j] ----------
// grid = B*H/256 = 128, block = 256; lane-major over b for coalesced gi/gh reads
__global__ __launch_bounds__(256) void gru_combine_kernel(
    const float* __restrict__ gi, const float* __restrict__ gh,
    const float* __restrict__ bih, const float* __restrict__ bhh,
    const float* __restrict__ hprev, int hstride,
    float* __restrict__ hnew, int hnewstride)
{
    int idx = blockIdx.x * blockDim.x + threadIdx.x;
    int b = idx & 63, j = idx >> 6;
    if (j >= HH) return;
    float ir = gi[j * BB + b]            + bih[j];
    float iz = gi[(HH + j) * BB + b]     + bih[HH + j];
    float in_ = gi[(2 * HH + j) * BB + b] + bih[2 * HH + j];
    float hr = gh[j * BB + b]            + bhh[j];
    float hz = gh[(HH + j) * BB + b]     + bhh[HH + j];
    float hn = gh[(2 * HH + j) * BB + b] + bhh[2 * HH + j];
    float r = sigmoidf_(ir + hr);
    float z = sigmoidf_(iz + hz);
    float n = tanhf(in_ + r * hn);
    float hp = hprev ? hprev[(long)b * hstride + j] : 0.f;
    hnew[(long)b * hnewstride + j] = (1.f - z) * n + z * hp;
}

// ---------- fused attention: scores -> softmax -> context ----------
// grid = B, block = 256
__global__ __launch_bounds__(256) void attn_kernel(
    const float* __restrict__ enc_states,  // [b][s][h]
    const float* __restrict__ hnew,        // [b][h] stride H
    float* __restrict__ context)           // [b][h]
{
    int b = blockIdx.x, t = threadIdx.x;
    __shared__ float hs[HH];
    __shared__ float sc[SS];
    for (int j = t; j < HH; j += 256) hs[j] = hnew[b * HH + j];
    __syncthreads();
    int wave = t >> 6, lane = t & 63;
    for (int sp = wave; sp < SS; sp += 4) {
        const float* es = enc_states + ((long)b * SS + sp) * HH;
        float p = 0.f;
        for (int k = lane; k < HH; k += 64) p += es[k] * hs[k];
        for (int o = 32; o; o >>= 1) p += __shfl_down(p, o);
        if (lane == 0) sc[sp] = p;
    }
    __syncthreads();
    if (t == 0) {
        float m = sc[0];
        for (int i = 1; i < SS; i++) m = fmaxf(m, sc[i]);
        float sum = 0.f;
        for (int i = 0; i < SS; i++) { float e = expf(sc[i] - m); sc[i] = e; sum += e; }
        float inv = 1.f / sum;
        for (int i = 0; i < SS; i++) sc[i] *= inv;
    }
    __syncthreads();
    for (int j = t; j < HH; j += 256) {
        float c = 0.f;
        for (int sp = 0; sp < SS; sp++) c += sc[sp] * enc_states[((long)b * SS + sp) * HH + j];
        context[b * HH + j] = c;
    }
}

// ---------- projection GEMM: logits[b][v] = cat[b][:]·proj_w[v][:] + pb[v] ----------
// grid = ceil(V/64) = 469, block = 256
__global__ __launch_bounds__(256) void proj_kernel(
    const float* __restrict__ hnew,     // [b][H] stride H
    const float* __restrict__ context,  // [b][H]
    const float* __restrict__ pw,       // [V][2H]
    const float* __restrict__ pb,       // [V]
    float* __restrict__ logits)         // [b][V]
{
    __shared__ float Wt[64][68];   // [k][v]
    __shared__ float Xt[64][68];   // [k][b]
    const int t  = threadIdx.x;
    const int tx = t & 15, ty = t >> 4;
    const int v0 = blockIdx.x * 64;
    const int bb = t & 63, kq = t >> 6;
    const int wkk = (t & 15) * 4, wjj = t >> 4;

    float acc[4][4];
    #pragma unroll
    for (int i = 0; i < 4; i++)
        #pragma unroll
        for (int j = 0; j < 4; j++) acc[i][j] = 0.f;

    for (int kb = 0; kb < 2 * HH; kb += 64) {
        #pragma unroll
        for (int r = 0; r < 4; r++) {
            int row = v0 + wjj + r * 16;
            if (row > VV - 1) row = VV - 1;
            const float4 w = *(const float4*)&pw[(long)row * (2 * HH) + kb + wkk];
            Wt[wkk + 0][wjj + r * 16] = w.x;
            Wt[wkk + 1][wjj + r * 16] = w.y;
            Wt[wkk + 2][wjj + r * 16] = w.z;
            Wt[wkk + 3][wjj + r * 16] = w.w;
        }
        {
            int kglob = kb + kq * 16;
            const float* src = (kglob < HH) ? (hnew + bb * HH + kglob)
                                            : (context + bb * HH + (kglob - HH));
            #pragma unroll
            for (int q = 0; q < 4; q++) {
                const float4 x = *(const float4*)&src[q * 4];
                Xt[kq * 16 + q * 4 + 0][bb] = x.x;
                Xt[kq * 16 + q * 4 + 1][bb] = x.y;
                Xt[kq * 16 + q * 4 + 2][bb] = x.z;
                Xt[kq * 16 + q * 4 + 3][bb] = x.w;
            }
        }
        __syncthreads();
        #pragma unroll 8
        for (int k = 0; k < 64; k++) {
            const float4 a = *(const float4*)&Wt[k][ty * 4];
            const float4 x = *(const float4*)&Xt[k][tx * 4];
            acc[0][0] += a.x * x.x; acc[0][1] += a.x * x.y; acc[0][2] += a.x * x.z; acc[0][3] += a.x * x.w;
            acc[1][0] += a.y * x.x; acc[1][1] += a.y * x.y; acc[1][2] += a.y * x.z; acc[1][3] += a.y * x.w;
            acc[2][0] += a.z * x.x; acc[2][1] += a.z * x.y; acc[2][2] += a.z * x.z; acc[2][3] += a.z * x.w;
            acc[3][0] += a.w * x.x; acc[3][1] += a.w * x.y; acc[3][2] += a.w * x.z; acc[3][3] += a.w * x.w;
        }
        __syncthreads();
    }

    const int vbase = v0 + ty * 4;
    #pragma unroll
    for (int jb = 0; jb < 4; jb++) {
        int b = tx * 4 + jb;
        if (vbase + 3 < VV) {
            float4 o;
            o.x = acc[0][jb] + pb[vbase + 0];
            o.y = acc[1][jb] + pb[vbase + 1];
            o.z = acc[2][jb] + pb[vbase + 2];
            o.w = acc[3][jb] + pb[vbase + 3];
            *(float4*)&logits[(long)b * VV + vbase] = o;
        } else {
            for (int i = 0; i < 4; i++)
                if (vbase + i < VV) logits[(long)b * VV + vbase + i] = acc[i][jb] + pb[vbase + i];
        }
    }
}

// ---------- per-row max/argmax/log-sum-exp + next token ----------
// grid = B, block = 256
__global__ __launch_bounds__(256) void reduce_kernel(
    const float* __restrict__ logits,  // [b][V] this step
    float* __restrict__ stats,         // [B] -> max + log(sum)
    int* __restrict__ tok,             // [B] next decoder input
    float* __restrict__ pred_out)      // d_out + s*B
{
    int b = blockIdx.x, t = threadIdx.x;
    const float* row = logits + (long)b * VV;
    float m = -INFINITY; int am = 0;
    for (int v = t; v < VV; v += 256) {
        float x = row[v];
        if (x > m) { m = x; am = v; }
    }
    __shared__ float mx[256];
    __shared__ int   ax[256];
    mx[t] = m; ax[t] = am;
    __syncthreads();
    for (int o = 128; o; o >>= 1) {
        if (t < o) {
            if (mx[t + o] > mx[t] || (mx[t + o] == mx[t] && ax[t + o] < ax[t])) {
                mx[t] = mx[t + o]; ax[t] = ax[t + o];
            }
        }
        __syncthreads();
    }
    float gm = mx[0];
    float s = 0.f;
    for (int v = t; v < VV; v += 256) s += expf(row[v] - gm);
    __shared__ float sm[256];
    sm[t] = s;
    __syncthreads();
    for (int o = 128; o; o >>= 1) {
        if (t < o) sm[t] += sm[t + o];
        __syncthreads();
    }
    if (t == 0) {
        stats[b] = gm + logf(sm[0]);
        tok[b] = ax[0];
        pred_out[b] = (float)ax[0];
    }
}

// ---------- batched final log-softmax normalize ----------
__global__ void normalize_kernel(float* __restrict__ dists, const float* __restrict__ stats) {
    const long total4 = (long)SS * BB * VV / 4;
    for (long i4 = (long)blockIdx.x * blockDim.x + threadIdx.x; i4 < total4;
         i4 += (long)gridDim.x * blockDim.x) {
        long i = i4 * 4;
        int sb = (int)(i / VV);
        float st = stats[sb];
        float4 x = *(float4*)&dists[i];
        x.x -= st; x.y -= st; x.z -= st; x.w -= st;
        *(float4*)&dists[i] = x;
    }
}

extern "C" void kernel_launch(void* const* d_in, const int* in_sizes, int n_in,
                              void* d_out, int out_size, void* d_ws, size_t ws_size,
                              hipStream_t stream) {
    const int*   input     = (const int*)  d_in[0];
    const float* enc_embed = (const float*)d_in[1];
    const float* enc_wih   = (const float*)d_in[2];
    const float* enc_whh   = (const float*)d_in[3];
    const float* enc_bih   = (const float*)d_in[4];
    const float* enc_bhh   = (const float*)d_in[5];
    const float* dec_embed = (const float*)d_in[6];
    const float* dec_wih   = (const float*)d_in[7];
    const float* dec_whh   = (const float*)d_in[8];
    const float* dec_bih   = (const float*)d_in[9];
    const float* dec_bhh   = (const float*)d_in[10];
    const float* proj_w    = (const float*)d_in[11];
    const float* proj_b    = (const float*)d_in[12];

    float* out       = (float*)d_out;
    float* pred_out  = out;            // S*B
    float* dists_out = out + SS * BB;  // S*B*V

    float* ws         = (float*)d_ws;
    float* enc_states = ws;                              // B*S*H
    float* gi         = enc_states + (long)BB * SS * HH; // G3*B
    float* gh         = gi + G3 * BB;
    float* hA         = gh + G3 * BB;                    // B*H
    float* hB         = hA + BB * HH;
    float* context    = hB + BB * HH;                    // B*H
    float* stats      = context + BB * HH;               // S*B
    int*   tok        = (int*)(stats + SS * BB);         // B

    // ---------------- encoder ----------------
    for (int s = 0; s < SS; s++) {
        const float* hprev = s ? enc_states + (long)(s - 1) * HH : nullptr;
        gates_kernel<<<G3 / 64, 256, 0, stream>>>(input + s, SS, enc_embed,
                                                  enc_wih, enc_whh,
                                                  hprev, SS * HH, gi, gh);
        gru_combine_kernel<<<BB * HH / 256, 256, 0, stream>>>(gi, gh, enc_bih, enc_bhh,
                                                              hprev, SS * HH,
                                                              enc_states + (long)s * HH, SS * HH);
    }

    // ---------------- decoder ----------------
    init_tok_kernel<<<1, 64, 0, stream>>>(tok);
    for (int s = 0; s < SS; s++) {
        const float* hprev; int hstride;
        if (s == 0) { hprev = enc_states + (long)(SS - 1) * HH; hstride = SS * HH; }
        else        { hprev = (s & 1) ? hA : hB;                hstride = HH; }
        float* hnew = (s & 1) ? hB : hA;

        gates_kernel<<<G3 / 64, 256, 0, stream>>>(tok, 1, dec_embed,
                                                  dec_wih, dec_whh,
                                                  hprev, hstride, gi, gh);
        gru_combine_kernel<<<BB * HH / 256, 256, 0, stream>>>(gi, gh, dec_bih, dec_bhh,
                                                              hprev, hstride, hnew, HH);
        attn_kernel<<<BB, 256, 0, stream>>>(enc_states, hnew, context);

        float* logits = dists_out + (long)s * BB * VV;
        proj_kernel<<<(VV + 63) / 64, 256, 0, stream>>>(hnew, context, proj_w, proj_b, logits);
        reduce_kernel<<<BB, 256, 0, stream>>>(logits, stats + s * BB, tok, pred_out + s * BB);
    }

    normalize_kernel<<<2048, 256, 0, stream>>>(dists_out, stats);
}

// Round 2
// 7432.788 us; speedup vs baseline: 1.4438x; 1.4438x over previous
//
#include <hip/hip_runtime.h>
#include <math.h>

#define BB 64
#define SS 48
#define EE 256
#define HH 512
#define VV 30000
#define G3 1536  // 3*H

typedef __attribute__((ext_vector_type(8))) short s8v;
typedef __attribute__((ext_vector_type(4))) short s4v;
typedef __attribute__((ext_vector_type(4))) float f4v;

__device__ __forceinline__ float sigmoidf_(float x) { return 1.f / (1.f + expf(-x)); }

// round-to-nearest-even float -> bf16 bits
__device__ __forceinline__ short f2bf(float x) {
    union { float f; unsigned u; } v; v.f = x;
    unsigned r = v.u + 0x7fffu + ((v.u >> 16) & 1u);
    return (short)(r >> 16);
}
__device__ __forceinline__ float bf2f(short h) {
    union { unsigned u; float f; } v; v.u = ((unsigned)(unsigned short)h) << 16;
    return v.f;
}

// ---------- tiny init ----------
__global__ void init_tok_kernel(int* tok) {
    if (threadIdx.x < BB) tok[threadIdx.x] = 0;
}

// ---------- split fp32 array into bf16 hi/lo ----------
__global__ __launch_bounds__(256) void split_kernel(
    const float* __restrict__ src, long n4,
    short* __restrict__ hi, short* __restrict__ lo)
{
    for (long i = (long)blockIdx.x * 256 + threadIdx.x; i < n4;
         i += (long)gridDim.x * 256) {
        const float4 x = *(const float4*)&src[i * 4];
        float xs[4] = {x.x, x.y, x.z, x.w};
        s4v h, l;
        #pragma unroll
        for (int j = 0; j < 4; j++) {
            short hh = f2bf(xs[j]);
            h[j] = hh;
            l[j] = f2bf(xs[j] - bf2f(hh));
        }
        *(s4v*)&hi[i * 4] = h;
        *(s4v*)&lo[i * 4] = l;
    }
}

// ---------- gates GEMM (fp32, unchanged from R1) ----------
__global__ __launch_bounds__(256) void gates_kernel(
    const int* __restrict__ tokens, int tok_stride,
    const float* __restrict__ embed,
    const float* __restrict__ wih, const float* __restrict__ whh,
    const float* __restrict__ hprev, int hstride,
    float* __restrict__ gi, float* __restrict__ gh)
{
    __shared__ float Wt[64][68];   // [k][j]
    __shared__ float Xt[64][68];   // [k][b]
    const int t  = threadIdx.x;
    const int tx = t & 15, ty = t >> 4;
    const int j0 = blockIdx.x * 64;
    const int bb = t & 63, kq = t >> 6;
    const int wkk = (t & 15) * 4, wjj = t >> 4;

    const long xrow = (long)tokens[bb * tok_stride] * EE;

    float acc[4][4];

    #pragma unroll
    for (int i = 0; i < 4; i++)
        #pragma unroll
        for (int j = 0; j < 4; j++) acc[i][j] = 0.f;

    for (int kb = 0; kb < EE; kb += 64) {
        #pragma unroll
        for (int r = 0; r < 4; r++) {
            int row = j0 + wjj + r * 16;
            const float4 w = *(const float4*)&wih[row * EE + kb + wkk];
            Wt[wkk + 0][wjj + r * 16] = w.x;
            Wt[wkk + 1][wjj + r * 16] = w.y;
            Wt[wkk + 2][wjj + r * 16] = w.z;
            Wt[wkk + 3][wjj + r * 16] = w.w;
        }
        {
            const float* src = embed + xrow + kb + kq * 16;
            #pragma unroll
            for (int q = 0; q < 4; q++) {
                const float4 x = *(const float4*)&src[q * 4];
                Xt[kq * 16 + q * 4 + 0][bb] = x.x;
                Xt[kq * 16 + q * 4 + 1][bb] = x.y;
                Xt[kq * 16 + q * 4 + 2][bb] = x.z;
                Xt[kq * 16 + q * 4 + 3][bb] = x.w;
            }
        }
        __syncthreads();
        #pragma unroll 8
        for (int k = 0; k < 64; k++) {
            const float4 a = *(const float4*)&Wt[k][ty * 4];
            const float4 x = *(const float4*)&Xt[k][tx * 4];
            acc[0][0] += a.x * x.x; acc[0][1] += a.x * x.y; acc[0][2] += a.x * x.z; acc[0][3] += a.x * x.w;
            acc[1][0] += a.y * x.x; acc[1][1] += a.y * x.y; acc[1][2] += a.y * x.z; acc[1][3] += a.y * x.w;
            acc[2][0] += a.z * x.x; acc[2][1] += a.z * x.y; acc[2][2] += a.z * x.z; acc[2][3] += a.z * x.w;
            acc[3][0] += a.w * x.x; acc[3][1] += a.w * x.y; acc[3][2] += a.w * x.z; acc[3][3] += a.w * x.w;
        }
        __syncthreads();
    }
    #pragma unroll
    for (int i = 0; i < 4; i++) {
        float4 o; o.x = acc[i][0]; o.y = acc[i][1]; o.z = acc[i][2]; o.w = acc[i][3];
        *(float4*)&gi[(j0 + ty * 4 + i) * BB + tx * 4] = o;
    }

    #pragma unroll
    for (int i = 0; i < 4; i++)
        #pragma unroll
        for (int j = 0; j < 4; j++) acc[i][j] = 0.f;

    if (hprev) {
        const float* hsrc = hprev + (long)bb * hstride;
        for (int kb = 0; kb < HH; kb += 64) {
            #pragma unroll
            for (int r = 0; r < 4; r++) {
                int row = j0 + wjj + r * 16;
                const float4 w = *(const float4*)&whh[row * HH + kb + wkk];
                Wt[wkk + 0][wjj + r * 16] = w.x;
                Wt[wkk + 1][wjj + r * 16] = w.y;
                Wt[wkk + 2][wjj + r * 16] = w.z;
                Wt[wkk + 3][wjj + r * 16] = w.w;
            }
            {
                const float* src = hsrc + kb + kq * 16;
                #pragma unroll
                for (int q = 0; q < 4; q++) {
                    const float4 x = *(const float4*)&src[q * 4];
                    Xt[kq * 16 + q * 4 + 0][bb] = x.x;
                    Xt[kq * 16 + q * 4 + 1][bb] = x.y;
                    Xt[kq * 16 + q * 4 + 2][bb] = x.z;
                    Xt[kq * 16 + q * 4 + 3][bb] = x.w;
                }
            }
            __syncthreads();
            #pragma unroll 8
            for (int k = 0; k < 64; k++) {
                const float4 a = *(const float4*)&Wt[k][ty * 4];
                const float4 x = *(const float4*)&Xt[k][tx * 4];
                acc[0][0] += a.x * x.x; acc[0][1] += a.x * x.y; acc[0][2] += a.x * x.z; acc[0][3] += a.x * x.w;
                acc[1][0] += a.y * x.x; acc[1][1] += a.y * x.y; acc[1][2] += a.y * x.z; acc[1][3] += a.y * x.w;
                acc[2][0] += a.z * x.x; acc[2][1] += a.z * x.y; acc[2][2] += a.z * x.z; acc[2][3] += a.z * x.w;
                acc[3][0] += a.w * x.x; acc[3][1] += a.w * x.y; acc[3][2] += a.w * x.z; acc[3][3] += a.w * x.w;
            }
            __syncthreads();
        }
    }
    #pragma unroll
    for (int i = 0; i < 4; i++) {
        float4 o; o.x = acc[i][0]; o.y = acc[i][1]; o.z = acc[i][2]; o.w = acc[i][3];
        *(float4*)&gh[(j0 + ty * 4 + i) * BB + tx * 4] = o;
    }
}

// ---------- GRU gate combine ----------
__global__ __launch_bounds__(256) void gru_combine_kernel(
    const float* __restrict__ gi, const float* __restrict__ gh,
    const float* __restrict__ bih, const float* __restrict__ bhh,
    const float* __restrict__ hprev, int hstride,
    float* __restrict__ hnew, int hnewstride)
{
    int idx = blockIdx.x * blockDim.x + threadIdx.x;
    int b = idx & 63, j = idx >> 6;
    if (j >= HH) return;
    float ir = gi[j * BB + b]            + bih[j];
    float iz = gi[(HH + j) * BB + b]     + bih[HH + j];
    float in_ = gi[(2 * HH + j) * BB + b] + bih[2 * HH + j];
    float hr = gh[j * BB + b]            + bhh[j];
    float hz = gh[(HH + j) * BB + b]     + bhh[HH + j];
    float hn = gh[(2 * HH + j) * BB + b] + bhh[2 * HH + j];
    float r = sigmoidf_(ir + hr);
    float z = sigmoidf_(iz + hz);
    float n = tanhf(in_ + r * hn);
    float hp = hprev ? hprev[(long)b * hstride + j] : 0.f;
    hnew[(long)b * hnewstride + j] = (1.f - z) * n + z * hp;
}

// ---------- fused attention: scores -> softmax -> context -> cat hi/lo ----------
__global__ __launch_bounds__(256) void attn_kernel(
    const float* __restrict__ enc_states,  // [b][s][h]
    const float* __restrict__ hnew,        // [b][h] stride H
    short* __restrict__ cat_hi,            // [b][2H] bf16 bits
    short* __restrict__ cat_lo)
{
    int b = blockIdx.x, t = threadIdx.x;
    __shared__ float hs[HH];
    __shared__ float ctxs[HH];
    __shared__ float sc[SS];
    for (int j = t; j < HH; j += 256) hs[j] = hnew[b * HH + j];
    __syncthreads();
    int wave = t >> 6, lane = t & 63;
    for (int sp = wave; sp < SS; sp += 4) {
        const float* es = enc_states + ((long)b * SS + sp) * HH;
        float p = 0.f;
        for (int k = lane; k < HH; k += 64) p += es[k] * hs[k];
        for (int o = 32; o; o >>= 1) p += __shfl_down(p, o);
        if (lane == 0) sc[sp] = p;
    }
    __syncthreads();
    if (t == 0) {
        float m = sc[0];
        for (int i = 1; i < SS; i++) m = fmaxf(m, sc[i]);
        float sum = 0.f;
        for (int i = 0; i < SS; i++) { float e = expf(sc[i] - m); sc[i] = e; sum += e; }
        float inv = 1.f / sum;
        for (int i = 0; i < SS; i++) sc[i] *= inv;
    }
    __syncthreads();
    for (int j = t; j < HH; j += 256) {
        float c = 0.f;
        for (int sp = 0; sp < SS; sp++) c += sc[sp] * enc_states[((long)b * SS + sp) * HH + j];
        ctxs[j] = c;
    }
    __syncthreads();
    for (int k = t; k < 2 * HH; k += 256) {
        float val = (k < HH) ? hs[k] : ctxs[k - HH];
        short h = f2bf(val);
        cat_hi[b * 2 * HH + k] = h;
        cat_lo[b * 2 * HH + k] = f2bf(val - bf2f(h));
    }
}

// ---------- projection via split-bf16 MFMA (3-term: exact to ~2^-16) ----------
// grid = ceil(V/64) = 469, block = 128 (2 waves, each wave: 32v x 64b)
__global__ __launch_bounds__(128) void proj_mfma_kernel(
    const short* __restrict__ pw_hi, const short* __restrict__ pw_lo,  // may be null
    const float* __restrict__ pw_f32,
    const short* __restrict__ cat_hi, const short* __restrict__ cat_lo,
    const float* __restrict__ pb,
    float* __restrict__ logits)
{
    __shared__ __attribute__((aligned(16))) short Ah[64][72];
    __shared__ __attribute__((aligned(16))) short Al[64][72];
    __shared__ __attribute__((aligned(16))) short Bh[64][72];
    __shared__ __attribute__((aligned(16))) short Bl[64][72];

    const int t    = threadIdx.x;
    const int lane = t & 63, wave = t >> 6;
    const int v0   = blockIdx.x * 64;
    const int srow = t >> 3, sc8 = t & 7;   // staging: 16 rows/pass, 8 x 16B per row

    f4v acc[2][4];
    #pragma unroll
    for (int i = 0; i < 2; i++)
        #pragma unroll
        for (int j = 0; j < 4; j++) acc[i][j] = (f4v){0.f, 0.f, 0.f, 0.f};

    for (int ks = 0; ks < 16; ks++) {
        const int kb = ks * 64;
        // ---- stage A (64 v-rows x 64 k) ----
        if (pw_hi) {
            #pragma unroll
            for (int p = 0; p < 4; p++) {
                int r = p * 16 + srow;
                long vrow = v0 + r; if (vrow >= VV) vrow = VV - 1;
                s8v h = *(const s8v*)&pw_hi[vrow * (2 * HH) + kb + sc8 * 8];
                s8v l = *(const s8v*)&pw_lo[vrow * (2 * HH) + kb + sc8 * 8];
                *(s8v*)&Ah[r][sc8 * 8] = h;
                *(s8v*)&Al[r][sc8 * 8] = l;
            }
        } else {
            #pragma unroll
            for (int p = 0; p < 4; p++) {
                int r = p * 16 + srow;
                long vrow = v0 + r; if (vrow >= VV) vrow = VV - 1;
                const float* src = &pw_f32[vrow * (2 * HH) + kb + sc8 * 8];
                const float4 f0 = *(const float4*)&src[0];
                const float4 f1 = *(const float4*)&src[4];
                float xs[8] = {f0.x, f0.y, f0.z, f0.w, f1.x, f1.y, f1.z, f1.w};
                s8v h, l;
                #pragma unroll
                for (int i = 0; i < 8; i++) {
                    short hh = f2bf(xs[i]);
                    h[i] = hh;
                    l[i] = f2bf(xs[i] - bf2f(hh));
                }
                *(s8v*)&Ah[r][sc8 * 8] = h;
                *(s8v*)&Al[r][sc8 * 8] = l;
            }
        }
        // ---- stage B (64 b-rows x 64 k) ----
        #pragma unroll
        for (int p = 0; p < 4; p++) {
            int r = p * 16 + srow;
            s8v h = *(const s8v*)&cat_hi[r * (2 * HH) + kb + sc8 * 8];
            s8v l = *(const s8v*)&cat_lo[r * (2 * HH) + kb + sc8 * 8];
            *(s8v*)&Bh[r][sc8 * 8] = h;
            *(s8v*)&Bl[r][sc8 * 8] = l;
        }
        __syncthreads();
        // ---- compute: 2 k-chunks of 32 ----
        #pragma unroll
        for (int kc = 0; kc < 64; kc += 32) {
            const int ko = kc + (lane >> 4) * 8;
            const int fr = lane & 15;
            s8v ah0 = *(s8v*)&Ah[wave * 32 + fr][ko];
            s8v ah1 = *(s8v*)&Ah[wave * 32 + 16 + fr][ko];
            s8v al0 = *(s8v*)&Al[wave * 32 + fr][ko];
            s8v al1 = *(s8v*)&Al[wave * 32 + 16 + fr][ko];
            s8v bh[4], bl[4];
            #pragma unroll
            for (int fb = 0; fb < 4; fb++) {
                bh[fb] = *(s8v*)&Bh[fb * 16 + fr][ko];
                bl[fb] = *(s8v*)&Bl[fb * 16 + fr][ko];
            }
            #pragma unroll
            for (int fb = 0; fb < 4; fb++) {
                acc[0][fb] = __builtin_amdgcn_mfma_f32_16x16x32_bf16(ah0, bh[fb], acc[0][fb], 0, 0, 0);
                acc[0][fb] = __builtin_amdgcn_mfma_f32_16x16x32_bf16(al0, bh[fb], acc[0][fb], 0, 0, 0);
                acc[0][fb] = __builtin_amdgcn_mfma_f32_16x16x32_bf16(ah0, bl[fb], acc[0][fb], 0, 0, 0);
                acc[1][fb] = __builtin_amdgcn_mfma_f32_16x16x32_bf16(ah1, bh[fb], acc[1][fb], 0, 0, 0);
                acc[1][fb] = __builtin_amdgcn_mfma_f32_16x16x32_bf16(al1, bh[fb], acc[1][fb], 0, 0, 0);
                acc[1][fb] = __builtin_amdgcn_mfma_f32_16x16x32_bf16(ah1, bl[fb], acc[1][fb], 0, 0, 0);
            }
        }
        __syncthreads();
    }

    // ---- store: D col = lane&15 (b), row = (lane>>4)*4 + reg (v) ----
    const int col = lane & 15;
    #pragma unroll
    for (int fv = 0; fv < 2; fv++) {
        int vbase = v0 + wave * 32 + fv * 16 + (lane >> 4) * 4;
        #pragma unroll
        for (int fb = 0; fb < 4; fb++) {
            int b = fb * 16 + col;
            if (vbase + 3 < VV) {
                const float4 pbv = *(const float4*)&pb[vbase];
                float4 o;
                o.x = acc[fv][fb][0] + pbv.x;
                o.y = acc[fv][fb][1] + pbv.y;
                o.z = acc[fv][fb][2] + pbv.z;
                o.w = acc[fv][fb][3] + pbv.w;
                *(float4*)&logits[(long)b * VV + vbase] = o;
            } else {
                for (int i = 0; i < 4; i++)
                    if (vbase + i < VV)
                        logits[(long)b * VV + vbase + i] = acc[fv][fb][i] + pb[vbase + i];
            }
        }
    }
}

// ---------- per-row max/argmax/log-sum-exp + next token + in-place normalize ----------
__global__ __launch_bounds__(256) void reduce_norm_kernel(
    float* __restrict__ logits,  // [b][V] this step (in d_out)
    int* __restrict__ tok,
    float* __restrict__ pred_out)
{
    int b = blockIdx.x, t = threadIdx.x;
    float* row = logits + (long)b * VV;
    float m = -INFINITY; int am = 0;
    for (int v = t * 4; v < VV; v += 1024) {
        float4 x = *(const float4*)&row[v];
        if (x.x > m) { m = x.x; am = v; }
        if (x.y > m) { m = x.y; am = v + 1; }
        if (x.z > m) { m = x.z; am = v + 2; }
        if (x.w > m) { m = x.w; am = v + 3; }
    }
    __shared__ float mx[256];
    __shared__ int   ax[256];
    __shared__ float sm[256];
    mx[t] = m; ax[t] = am;
    __syncthreads();
    for (int o = 128; o; o >>= 1) {
        if (t < o) {
            if (mx[t + o] > mx[t] || (mx[t + o] == mx[t] && ax[t + o] < ax[t])) {
                mx[t] = mx[t + o]; ax[t] = ax[t + o];
            }
        }
        __syncthreads();
    }
    float gm = mx[0];
    float s = 0.f;
    for (int v = t * 4; v < VV; v += 1024) {
        float4 x = *(const float4*)&row[v];
        s += expf(x.x - gm) + expf(x.y - gm) + expf(x.z - gm) + expf(x.w - gm);
    }
    sm[t] = s;
    __syncthreads();
    for (int o = 128; o; o >>= 1) {
        if (t < o) sm[t] += sm[t + o];
        __syncthreads();
    }
    float lse = gm + logf(sm[0]);
    for (int v = t * 4; v < VV; v += 1024) {
        float4 x = *(const float4*)&row[v];
        x.x -= lse; x.y -= lse; x.z -= lse; x.w -= lse;
        *(float4*)&row[v] = x;
    }
    if (t == 0) {
        tok[b] = ax[0];
        pred_out[b] = (float)ax[0];
    }
}

extern "C" void kernel_launch(void* const* d_in, const int* in_sizes, int n_in,
                              void* d_out, int out_size, void* d_ws, size_t ws_size,
                              hipStream_t stream) {
    const int*   input     = (const int*)  d_in[0];
    const float* enc_embed = (const float*)d_in[1];
    const float* enc_wih   = (const float*)d_in[2];
    const float* enc_whh   = (const float*)d_in[3];
    const float* enc_bih   = (const float*)d_in[4];
    const float* enc_bhh   = (const float*)d_in[5];
    const float* dec_embed = (const float*)d_in[6];
    const float* dec_wih   = (const float*)d_in[7];
    const float* dec_whh   = (const float*)d_in[8];
    const float* dec_bih   = (const float*)d_in[9];
    const float* dec_bhh   = (const float*)d_in[10];
    const float* proj_w    = (const float*)d_in[11];
    const float* proj_b    = (const float*)d_in[12];

    float* out       = (float*)d_out;
    float* pred_out  = out;            // S*B
    float* dists_out = out + SS * BB;  // S*B*V

    float* ws = (float*)d_ws;
    long off = 0;
    float* enc_states = ws + off; off += (long)BB * SS * HH;   // 1,572,864
    float* gi         = ws + off; off += G3 * BB;              // 98,304
    float* gh         = ws + off; off += G3 * BB;
    float* hA         = ws + off; off += BB * HH;
    float* hB         = ws + off; off += BB * HH;
    short* cat_hi     = (short*)(ws + off); off += BB * 2 * HH / 2;  // 32,768 float-slots
    short* cat_lo     = (short*)(ws + off); off += BB * 2 * HH / 2;
    int*   tok        = (int*)(ws + off);   off += BB;
    const long pw_elems = (long)VV * 2 * HH;  // 30,720,000
    bool use_split = ((long)ws_size >= (off + pw_elems) * 4 + 1024);
    short* pw_hi = nullptr;
    short* pw_lo = nullptr;
    if (use_split) {
        pw_hi = (short*)(ws + off); off += pw_elems / 2;
        pw_lo = (short*)(ws + off); off += pw_elems / 2;
        split_kernel<<<2048, 256, 0, stream>>>(proj_w, pw_elems / 4, pw_hi, pw_lo);
    }

    // ---------------- encoder ----------------
    for (int s = 0; s < SS; s++) {
        const float* hprev = s ? enc_states + (long)(s - 1) * HH : nullptr;
        gates_kernel<<<G3 / 64, 256, 0, stream>>>(input + s, SS, enc_embed,
                                                  enc_wih, enc_whh,
                                                  hprev, SS * HH, gi, gh);
        gru_combine_kernel<<<BB * HH / 256, 256, 0, stream>>>(gi, gh, enc_bih, enc_bhh,
                                                              hprev, SS * HH,
                                                              enc_states + (long)s * HH, SS * HH);
    }

    // ---------------- decoder ----------------
    init_tok_kernel<<<1, 64, 0, stream>>>(tok);
    for (int s = 0; s < SS; s++) {
        const float* hprev; int hstride;
        if (s == 0) { hprev = enc_states + (long)(SS - 1) * HH; hstride = SS * HH; }
        else        { hprev = (s & 1) ? hA : hB;                hstride = HH; }
        float* hnew = (s & 1) ? hB : hA;

        gates_kernel<<<G3 / 64, 256, 0, stream>>>(tok, 1, dec_embed,
                                                  dec_wih, dec_whh,
                                                  hprev, hstride, gi, gh);
        gru_combine_kernel<<<BB * HH / 256, 256, 0, stream>>>(gi, gh, dec_bih, dec_bhh,
                                                              hprev, hstride, hnew, HH);
        attn_kernel<<<BB, 256, 0, stream>>>(enc_states, hnew, cat_hi, cat_lo);

        float* logits = dists_out + (long)s * BB * VV;
        proj_mfma_kernel<<<(VV + 63) / 64, 128, 0, stream>>>(pw_hi, pw_lo, proj_w,
                                                             cat_hi, cat_lo, proj_b, logits);
        reduce_norm_kernel<<<BB, 256, 0, stream>>>(logits, tok, pred_out + s * BB);
    }
}